// Round 2
// baseline (272.983 us; speedup 1.0000x reference)
//
#include <hip/hip_runtime.h>
#include <math.h>

#define NSEG 2048
#define ROW 65
#define NK (65 * 65)
#define PPT 8
#define SCALE 1073741824.0  // 2^30 fixed-point scale

// ---------------- precompute piecewise-linear table for g(x) ----------------
// g(x) = sum_i W3[i] * relu(z_i(x)),  z_i affine per coarse interval between
// sorted breakpoints t_j = -b1[j]/W1[j].  Per coarse interval k we store the
// sorted outer-relu crossings (fine knots) and cumulative (a,b) coefficients
// so g(x) = a*x + b on every fine sub-interval.
__global__ __launch_bounds__(256) void k_precompute(
    const float* __restrict__ W1, const float* __restrict__ b1,
    const float* __restrict__ W2, const float* __restrict__ b2,
    const float* __restrict__ W3,
    unsigned long long* __restrict__ pooled, int* __restrict__ counts,
    float* __restrict__ bpg, float* __restrict__ knots, float2* __restrict__ coef)
{
    __shared__ float As[65][64];
    __shared__ float Bs[65][64];
    __shared__ float traw[64];
    __shared__ float bps[64];
    const int tid = threadIdx.x;

    // zero the accumulators (harness poisons ws; must re-zero every call)
    for (int i = tid; i < NSEG; i += 256) { pooled[i] = 0ull; counts[i] = 0; }

    // breakpoints (W1[j]==0 -> no kink, park sentinel at +3e38)
    if (tid < 64) {
        float w = W1[tid], b = b1[tid];
        traw[tid] = (w != 0.0f) ? (-b / w) : 3.0e38f;
    }
    __syncthreads();
    if (tid < 64) {  // stable rank sort of 64 values
        float t = traw[tid];
        int r = 0;
        for (int j = 0; j < 64; ++j) {
            float o = traw[j];
            r += (o < t) || (o == t && j < tid);
        }
        bps[r] = t;
    }
    __syncthreads();
    if (tid < 64) bpg[tid] = bps[tid];

    // affine coeffs of z_i on each coarse interval: z_i = A*x + B
    for (int p = tid; p < 65 * 64; p += 256) {
        int k = p >> 6, i = p & 63;
        float lo = (k == 0) ? (bps[0] - 1.0f) : bps[k - 1];
        float hi = (k == 64) ? (bps[63] + 1.0f) : bps[k];
        float xm = lo + 0.5f * (hi - lo);  // avoids overflow with sentinel
        float a = 0.0f, b = b2[i];
        for (int j = 0; j < 64; ++j) {
            float w1 = W1[j];
            if (w1 * xm + b1[j] > 0.0f) {  // inner relu active on this interval
                float w2 = W2[i * 64 + j];
                a += w2 * w1;
                b += w2 * b1[j];
            }
        }
        As[k][i] = a;
        Bs[k][i] = b;
    }
    __syncthreads();

    // per coarse interval: fine knots (outer-relu crossings) + cumulative (a,b)
    const int lane = tid & 63;
    const int wv = tid >> 6;
    for (int k = wv; k <= 64; k += 4) {  // one wave per interval, 4 waves
        float a = As[k][lane], b = Bs[k][lane];
        float w3 = W3[lane];
        float lo = (k == 0) ? -INFINITY : bps[k - 1];
        float hi = (k == 64) ? INFINITY : bps[k];
        float c = INFINITY, da = 0.0f, db = 0.0f;
        if (a != 0.0f) {
            float cc = -b / a;
            if (cc > lo && cc < hi) {  // valid crossing strictly inside
                float s = (a > 0.0f) ? 1.0f : -1.0f;  // z turns on (+) or off (-)
                c = cc; da = s * w3 * a; db = s * w3 * b;
            }
        }
        // active set just right of the left edge
        bool act;
        if (k == 0) act = (a < 0.0f) || (a == 0.0f && b > 0.0f);
        else { float v = a * lo + b; act = (v > 0.0f) || (v == 0.0f && a > 0.0f); }
        float a0 = act ? w3 * a : 0.0f;
        float b0 = act ? w3 * b : 0.0f;
        for (int d = 32; d; d >>= 1) { a0 += __shfl_xor(a0, d); b0 += __shfl_xor(b0, d); }

        // stable rank sort of crossings by c (invalid = +inf go last)
        int rank = 0;
        for (int l = 0; l < 64; ++l) {
            float o = __shfl(c, l);
            rank += (o < c) || (o == c && l < lane);
        }
        // inverse permutation: lane m pulls element with rank == m
        int src = 0;
        for (int l = 0; l < 64; ++l) {
            int r = __shfl(rank, l);
            if (r == lane) src = l;
        }
        float cs  = __shfl(c, src);
        float das = __shfl(da, src);
        float dbs = __shfl(db, src);
        // inclusive scan of deltas in sorted order
        for (int d = 1; d < 64; d <<= 1) {
            float ta = __shfl_up(das, d);
            float tb = __shfl_up(dbs, d);
            if (lane >= d) { das += ta; dbs += tb; }
        }
        knots[k * ROW + lane] = cs;
        if (lane == 0) coef[k * ROW] = make_float2(a0, b0);
        coef[k * ROW + lane + 1] = make_float2(a0 + das, b0 + dbs);
    }
}

// ---------------- eval: g(x) per point + segmented fixed-point accumulation ----
__global__ __launch_bounds__(256) void k_eval(
    const float* __restrict__ x, const int* __restrict__ batch,
    const float* __restrict__ bpg, const float* __restrict__ knots,
    const float2* __restrict__ coef,
    unsigned long long* __restrict__ pooled, int* __restrict__ counts, int n)
{
    __shared__ float bps[64];
    __shared__ float kn[NK];      // stride 65 -> bank (k+j)%32, conflict-light
    __shared__ float2 cf[NK];
    const int tid = threadIdx.x;
    for (int i = tid; i < 64; i += 256) bps[i] = bpg[i];
    for (int i = tid; i < NK; i += 256) { kn[i] = knots[i]; cf[i] = coef[i]; }
    __syncthreads();

    long long base = ((long long)blockIdx.x * 256 + tid) * PPT;
    if (base >= n) return;  // n % PPT == 0, whole-thread tail

    const float4* xp = (const float4*)(x + base);
    float4 x0 = xp[0], x1 = xp[1];
    const int4* bt = (const int4*)(batch + base);
    int4 s0 = bt[0], s1 = bt[1];
    float xs[PPT] = {x0.x, x0.y, x0.z, x0.w, x1.x, x1.y, x1.z, x1.w};
    int   ss[PPT] = {s0.x, s0.y, s0.z, s0.w, s1.x, s1.y, s1.z, s1.w};

    int curSeg = -1; long long acc = 0; int cnt = 0;
#pragma unroll
    for (int p = 0; p < PPT; ++p) {
        float xv = xs[p];
        int k = 0;  // branchless binary search: k = #{bps <= xv} in [0,64]
#pragma unroll
        for (int ofs = 32; ofs >= 1; ofs >>= 1)
            if (bps[k + ofs - 1] <= xv) k += ofs;
        k += (k < 64 && bps[k] <= xv) ? 1 : 0;
        const int kb = k * ROW;
        int j = 0;
#pragma unroll
        for (int ofs = 32; ofs >= 1; ofs >>= 1)
            if (kn[kb + j + ofs - 1] <= xv) j += ofs;
        j += (j < 64 && kn[kb + j] <= xv) ? 1 : 0;
        float2 ab = cf[kb + j];
        float g = fmaf(ab.x, xv, ab.y);
        long long q = (long long)((double)g * SCALE);  // exact to 2^-30
        int s = ss[p];
        if (s != curSeg) {
            if (cnt) {
                atomicAdd(&pooled[curSeg], (unsigned long long)acc);
                atomicAdd(&counts[curSeg], cnt);
            }
            curSeg = s; acc = q; cnt = 1;
        } else { acc += q; ++cnt; }
    }
    if (cnt) {
        atomicAdd(&pooled[curSeg], (unsigned long long)acc);
        atomicAdd(&counts[curSeg], cnt);
    }
}

// ---------------- per-segment weight ----------------
__global__ void k_weights(const unsigned long long* __restrict__ pooled,
                          const int* __restrict__ counts,
                          const float* __restrict__ b3,
                          float* __restrict__ weights)
{
    int s = blockIdx.x * blockDim.x + threadIdx.x;
    if (s >= NSEG) return;
    long long p = (long long)pooled[s];
    int c = counts[s];
    double mean = ((double)p / SCALE) / (double)(c > 0 ? c : 1);
    float w = (float)(mean + (double)b3[0]);
    weights[s] = fmaxf(w, 0.0f);
}

// ---------------- broadcast back to points ----------------
__global__ __launch_bounds__(256) void k_scatter(
    const int* __restrict__ batch, const float* __restrict__ weights,
    float* __restrict__ out, int n)
{
    long long base = ((long long)blockIdx.x * 256 + threadIdx.x) * PPT;
    if (base >= n) return;
    const int4* bt = (const int4*)(batch + base);
    int4 b0 = bt[0], b1 = bt[1];
    float4 o0, o1;
    o0.x = weights[b0.x];  // sorted batch -> ~1 distinct line per wave, L1 hit
    o0.y = weights[b0.y];
    o0.z = weights[b0.z];
    o0.w = weights[b0.w];
    o1.x = weights[b1.x];
    o1.y = weights[b1.y];
    o1.z = weights[b1.z];
    o1.w = weights[b1.w];
    float4* op = (float4*)(out + base);
    op[0] = o0;
    op[1] = o1;
}

extern "C" void kernel_launch(void* const* d_in, const int* in_sizes, int n_in,
                              void* d_out, int out_size, void* d_ws, size_t ws_size,
                              hipStream_t stream)
{
    const float* x   = (const float*)d_in[0];
    const int* batch = (const int*)d_in[1];
    const float* W1 = (const float*)d_in[2];
    const float* b1 = (const float*)d_in[3];
    const float* W2 = (const float*)d_in[4];
    const float* b2 = (const float*)d_in[5];
    const float* W3 = (const float*)d_in[6];
    const float* b3 = (const float*)d_in[7];
    float* out = (float*)d_out;
    const int n = in_sizes[0];

    char* ws = (char*)d_ws;
    unsigned long long* pooled = (unsigned long long*)ws;   // 2048*8  = 16384
    int*    counts  = (int*)(ws + 16384);                   // 2048*4  =  8192
    float*  weights = (float*)(ws + 24576);                 // 2048*4  =  8192
    float*  bpg     = (float*)(ws + 32768);                 // 64*4    =   256
    float*  knots   = (float*)(ws + 33024);                 // 65*65*4 = 16900 (pad to 16912)
    float2* coef    = (float2*)(ws + 33024 + 16912);        // 65*65*8 = 33800 -> total ~84 KB

    k_precompute<<<1, 256, 0, stream>>>(W1, b1, W2, b2, W3, pooled, counts, bpg, knots, coef);

    const int blocks = (int)((n + 256LL * PPT - 1) / (256LL * PPT));
    k_eval<<<blocks, 256, 0, stream>>>(x, batch, bpg, knots, coef, pooled, counts, n);
    k_weights<<<(NSEG + 255) / 256, 256, 0, stream>>>(pooled, counts, b3, weights);
    k_scatter<<<blocks, 256, 0, stream>>>(batch, weights, out, n);
}

// Round 3
// 94.902 us; speedup vs baseline: 2.8765x; 2.8765x over previous
//
#include <hip/hip_runtime.h>
#include <math.h>

#define NSEG 2048
#define ROW 65
#define MMAX 4226          // flat knot capacity incl sentinel (max M = 64*65+64 = 4224)
#define NC 4096            // grid cells
#define GLO (-9.0f)
#define GHI (9.0f)
#define DXF ((GHI - GLO) / NC)
#define INVDX (NC / (GHI - GLO))
#define PPT 16
#define SPPT 8
#define SCALE 1073741824.0  // 2^30 fixed point

// ---- k_pre_a: zero accumulators, sort inner-relu breakpoints (1 block) ----
__global__ __launch_bounds__(256) void k_pre_a(
    const float* __restrict__ W1, const float* __restrict__ b1,
    unsigned long long* __restrict__ pooled, int* __restrict__ counts,
    float* __restrict__ bpg)
{
    __shared__ float traw[64];
    __shared__ float bps[64];
    const int tid = threadIdx.x;
    for (int i = tid; i < NSEG; i += 256) { pooled[i] = 0ull; counts[i] = 0; }
    if (tid < 64) {
        float w = W1[tid], b = b1[tid];
        traw[tid] = (w != 0.0f) ? (-b / w) : 3.0e38f;
    }
    __syncthreads();
    if (tid < 64) {  // stable rank sort
        float t = traw[tid];
        int r = 0;
        for (int j = 0; j < 64; ++j) {
            float o = traw[j];
            r += (o < t) || (o == t && j < tid);
        }
        bps[r] = t;
    }
    __syncthreads();
    if (tid < 64) bpg[tid] = bps[tid];
}

// ---- k_pre_b: one coarse interval per block (65 blocks x 64 threads) ----
__global__ __launch_bounds__(64) void k_pre_b(
    const float* __restrict__ W1, const float* __restrict__ b1,
    const float* __restrict__ W2, const float* __restrict__ b2,
    const float* __restrict__ W3, const float* __restrict__ bpg,
    float* __restrict__ knots, float2* __restrict__ coef, int* __restrict__ nvalid)
{
    __shared__ float bps[64];
    const int lane = threadIdx.x;
    const int k = blockIdx.x;
    bps[lane] = bpg[lane];
    __syncthreads();

    // affine coeffs of z_i (i = lane) on interval k: z = a*x + b
    float lof = (k == 0) ? (bps[0] - 1.0f) : bps[k - 1];
    float hif = (k == 64) ? (bps[63] + 1.0f) : bps[k];
    float xm = lof + 0.5f * (hif - lof);
    float a = 0.0f, b = b2[lane];
    for (int j = 0; j < 64; ++j) {
        float w1 = W1[j];
        if (w1 * xm + b1[j] > 0.0f) {
            float w2 = W2[lane * 64 + j];
            a += w2 * w1;
            b += w2 * b1[j];
        }
    }

    // outer-relu crossing of z_i inside the open interval
    float w3 = W3[lane];
    float lo = (k == 0) ? -INFINITY : bps[k - 1];
    float hi = (k == 64) ? INFINITY : bps[k];
    float c = INFINITY, da = 0.0f, db = 0.0f;
    if (a != 0.0f) {
        float cc = -b / a;
        if (cc > lo && cc < hi) {
            float s = (a > 0.0f) ? 1.0f : -1.0f;
            c = cc; da = s * w3 * a; db = s * w3 * b;
        }
    }
    // active set just right of left edge -> (a0,b0)
    bool act;
    if (k == 0) act = (a < 0.0f) || (a == 0.0f && b > 0.0f);
    else { float v = a * lo + b; act = (v > 0.0f) || (v == 0.0f && a > 0.0f); }
    float a0 = act ? w3 * a : 0.0f;
    float b0 = act ? w3 * b : 0.0f;
    for (int d = 32; d; d >>= 1) { a0 += __shfl_xor(a0, d); b0 += __shfl_xor(b0, d); }

    // stable rank sort of crossings (inf = invalid go last)
    int rank = 0;
    for (int l = 0; l < 64; ++l) {
        float o = __shfl(c, l);
        rank += (o < c) || (o == c && l < lane);
    }
    int src = 0;
    for (int l = 0; l < 64; ++l) {
        int r = __shfl(rank, l);
        if (r == lane) src = l;
    }
    float cs  = __shfl(c, src);
    float das = __shfl(da, src);
    float dbs = __shfl(db, src);
    for (int d = 1; d < 64; d <<= 1) {  // inclusive scan in sorted order
        float ta = __shfl_up(das, d);
        float tb = __shfl_up(dbs, d);
        if (lane >= d) { das += ta; dbs += tb; }
    }
    knots[k * ROW + lane] = cs;
    if (lane == 0) coef[k * ROW] = make_float2(a0, b0);
    coef[k * ROW + lane + 1] = make_float2(a0 + das, b0 + dbs);

    unsigned long long vm = __ballot(isfinite(c));
    if (lane == 0) nvalid[k] = (int)__popcll(vm);
}

// ---- k_pre_c: flatten (k,j) tables into one sorted knot array + grid (1 block) ----
// Flat order per k: nvalid[k] fine knots, then coarse bps[k] (k<64). Globally sorted
// because fine knots lie strictly inside (bps[k-1], bps[k]).  m = #{T <= x} selects
// the SAME coefficient as the old two-level search (cf rows are constant past nvalid).
__global__ __launch_bounds__(256) void k_pre_c(
    const float* __restrict__ bpg, float* __restrict__ knots,
    float2* __restrict__ coef, const int* __restrict__ nvalid,
    unsigned short* __restrict__ baseg)
{
    __shared__ float  T_s[MMAX];
    __shared__ float2 C_s[MMAX];
    __shared__ int off[66];
    const int tid = threadIdx.x;
    if (tid == 0) {
        int o = 0;
        for (int k = 0; k < 65; ++k) { off[k] = o; o += nvalid[k] + 1; }
        off[65] = o;  // = M + 1 coef entries; M = o - 1 knots
    }
    __syncthreads();
    const int M = off[65] - 1;

    // phase 1: gather old layout -> flat LDS
    for (int p = tid; p < 65 * ROW; p += 256) {
        int k = p / ROW, j = p - k * ROW;
        int nv = nvalid[k];
        int o = off[k];
        if (j < nv) T_s[o + j] = knots[k * ROW + j];
        else if (j == nv && k < 64) T_s[o + j] = bpg[k];
        if (j <= nv) C_s[o + j] = coef[k * ROW + j];
    }
    float2 lastC = coef[64 * ROW + nvalid[64]];
    __syncthreads();
    for (int i = M + tid; i < MMAX; i += 256) T_s[i] = INFINITY;     // knot sentinels
    for (int i = M + 1 + tid; i < MMAX; i += 256) C_s[i] = lastC;    // coef pad
    __syncthreads();

    // phase 2: write flat tables back (in-place over knots/coef buffers) + grid
    for (int i = tid; i < MMAX; i += 256) knots[i] = T_s[i];
    for (int i = tid; i < MMAX; i += 256) coef[i] = C_s[i];
    for (int c = tid; c < NC; c += 256) {
        float left = GLO + c * DXF;
        int lo = 0, hi = M;  // lower bound: #{T <= left}
        while (lo < hi) { int mid = (lo + hi) >> 1; if (T_s[mid] <= left) lo = mid + 1; else hi = mid; }
        baseg[c] = (unsigned short)lo;
    }
}

// ---- eval: grid lookup + short scan + segmented fixed-point accumulation ----
__global__ __launch_bounds__(256) void k_eval(
    const float* __restrict__ x, const int* __restrict__ batch,
    const float* __restrict__ Tf, const float2* __restrict__ Cf,
    const unsigned short* __restrict__ baseg,
    unsigned long long* __restrict__ pooled, int* __restrict__ counts, int n)
{
    __shared__ float  T_s[MMAX];
    __shared__ float2 C_s[MMAX];
    __shared__ unsigned short base_s[NC];
    const int tid = threadIdx.x;
    for (int i = tid; i < MMAX; i += 256) T_s[i] = Tf[i];
    for (int i = tid; i < MMAX; i += 256) C_s[i] = Cf[i];
    for (int i = tid; i < NC / 2; i += 256)
        ((unsigned int*)base_s)[i] = ((const unsigned int*)baseg)[i];
    __syncthreads();

    long long base = ((long long)blockIdx.x * 256 + tid) * PPT;
    if (base >= n) return;  // n % PPT == 0 -> whole-thread tail

    float xs[PPT]; int ss[PPT];
    const float4* xp = (const float4*)(x + base);
    const int4*   bp = (const int4*)(batch + base);
#pragma unroll
    for (int v = 0; v < PPT / 4; ++v) {
        float4 xv4 = xp[v]; int4 s4 = bp[v];
        xs[4 * v + 0] = xv4.x; xs[4 * v + 1] = xv4.y; xs[4 * v + 2] = xv4.z; xs[4 * v + 3] = xv4.w;
        ss[4 * v + 0] = s4.x;  ss[4 * v + 1] = s4.y;  ss[4 * v + 2] = s4.z;  ss[4 * v + 3] = s4.w;
    }

    int curSeg = -1; long long acc = 0; int cnt = 0;
#pragma unroll
    for (int p = 0; p < PPT; ++p) {
        float xv = xs[p];
        int m;
        if (xv >= GLO) {
            int c = (int)((xv - GLO) * INVDX);
            c = c < NC - 1 ? c : NC - 1;
            if (c > 0 && GLO + c * DXF > xv) --c;  // fp rounding guard
            m = base_s[c];
        } else m = 0;
        while (T_s[m] <= xv) ++m;  // sentinel inf terminates; avg ~1-2 steps
        float2 ab = C_s[m];
        float g = fmaf(ab.x, xv, ab.y);
        long long q = (long long)((double)g * SCALE);
        int s = ss[p];
        if (s != curSeg) {
            if (cnt) {
                atomicAdd(&pooled[curSeg], (unsigned long long)acc);
                atomicAdd(&counts[curSeg], cnt);
            }
            curSeg = s; acc = q; cnt = 1;
        } else { acc += q; ++cnt; }
    }
    if (cnt) {
        atomicAdd(&pooled[curSeg], (unsigned long long)acc);
        atomicAdd(&counts[curSeg], cnt);
    }
}

// ---- per-segment weight ----
__global__ void k_weights(const unsigned long long* __restrict__ pooled,
                          const int* __restrict__ counts,
                          const float* __restrict__ b3,
                          float* __restrict__ weights)
{
    int s = blockIdx.x * blockDim.x + threadIdx.x;
    if (s >= NSEG) return;
    long long p = (long long)pooled[s];
    int c = counts[s];
    double mean = ((double)p / SCALE) / (double)(c > 0 ? c : 1);
    float w = (float)(mean + (double)b3[0]);
    weights[s] = fmaxf(w, 0.0f);
}

// ---- broadcast back to points ----
__global__ __launch_bounds__(256) void k_scatter(
    const int* __restrict__ batch, const float* __restrict__ weights,
    float* __restrict__ out, int n)
{
    long long base = ((long long)blockIdx.x * 256 + threadIdx.x) * SPPT;
    if (base >= n) return;
    const int4* bt = (const int4*)(batch + base);
    int4 b0 = bt[0], b1 = bt[1];
    float4 o0, o1;
    o0.x = weights[b0.x];  // sorted batch -> ~1 distinct line per wave, L1 hit
    o0.y = weights[b0.y];
    o0.z = weights[b0.z];
    o0.w = weights[b0.w];
    o1.x = weights[b1.x];
    o1.y = weights[b1.y];
    o1.z = weights[b1.z];
    o1.w = weights[b1.w];
    float4* op = (float4*)(out + base);
    op[0] = o0;
    op[1] = o1;
}

extern "C" void kernel_launch(void* const* d_in, const int* in_sizes, int n_in,
                              void* d_out, int out_size, void* d_ws, size_t ws_size,
                              hipStream_t stream)
{
    const float* x   = (const float*)d_in[0];
    const int* batch = (const int*)d_in[1];
    const float* W1 = (const float*)d_in[2];
    const float* b1 = (const float*)d_in[3];
    const float* W2 = (const float*)d_in[4];
    const float* b2 = (const float*)d_in[5];
    const float* W3 = (const float*)d_in[6];
    const float* b3 = (const float*)d_in[7];
    float* out = (float*)d_out;
    const int n = in_sizes[0];

    char* ws = (char*)d_ws;
    unsigned long long* pooled = (unsigned long long*)ws;   // 16384
    int*    counts  = (int*)(ws + 16384);                   // 8192
    float*  weights = (float*)(ws + 24576);                 // 8192
    float*  bpg     = (float*)(ws + 32768);                 // 256
    int*    nvalid  = (int*)(ws + 33024);                   // 272 (65*4 padded)
    float*  knots   = (float*)(ws + 33296);                 // 16912 (holds 65x65 then flat T[MMAX])
    float2* coef    = (float2*)(ws + 50208);                // 33808 (holds 65x65 then flat C[MMAX])
    unsigned short* baseg = (unsigned short*)(ws + 84016);  // 8192  -> total ~92 KB

    k_pre_a<<<1, 256, 0, stream>>>(W1, b1, pooled, counts, bpg);
    k_pre_b<<<65, 64, 0, stream>>>(W1, b1, W2, b2, W3, bpg, knots, coef, nvalid);
    k_pre_c<<<1, 256, 0, stream>>>(bpg, knots, coef, nvalid, baseg);

    const int eblocks = (int)((n + 256LL * PPT - 1) / (256LL * PPT));
    k_eval<<<eblocks, 256, 0, stream>>>(x, batch, knots, coef, baseg, pooled, counts, n);
    k_weights<<<(NSEG + 255) / 256, 256, 0, stream>>>(pooled, counts, b3, weights);
    const int sblocks = (int)((n + 256LL * SPPT - 1) / (256LL * SPPT));
    k_scatter<<<sblocks, 256, 0, stream>>>(batch, weights, out, n);
}

// Round 4
// 62.276 us; speedup vs baseline: 4.3834x; 1.5239x over previous
//
#include <hip/hip_runtime.h>
#include <math.h>

#define NSEG 2048
#define ROW 65
#define MMAX 4226          // max flat coef entries (M+1), M <= 64*65+64 = 4224
#define TCAP 4240          // flat knot array capacity incl window-read padding
#define NC 4096            // grid cells
#define GLO (-9.0f)
#define GHI (9.0f)
#define DXF ((GHI - GLO) / NC)
#define INVDX (NC / (GHI - GLO))
#define PPT 8
#define SPPT 8
#define CAP 64             // per-block segment-aggregation slots
#define SCALEF 1073741824.0f  // 2^30 (exact exponent shift in fp32)
#define SCALE  1073741824.0

// ---- k_pre_a: zero accumulators, sort inner-relu breakpoints (1 block) ----
__global__ __launch_bounds__(256) void k_pre_a(
    const float* __restrict__ W1, const float* __restrict__ b1,
    unsigned long long* __restrict__ pooled, int* __restrict__ counts,
    float* __restrict__ bpg)
{
    __shared__ float traw[64];
    __shared__ float bps[64];
    const int tid = threadIdx.x;
    for (int i = tid; i < NSEG; i += 256) { pooled[i] = 0ull; counts[i] = 0; }
    if (tid < 64) {
        float w = W1[tid], b = b1[tid];
        traw[tid] = (w != 0.0f) ? (-b / w) : 3.0e38f;
    }
    __syncthreads();
    if (tid < 64) {  // stable rank sort
        float t = traw[tid];
        int r = 0;
        for (int j = 0; j < 64; ++j) {
            float o = traw[j];
            r += (o < t) || (o == t && j < tid);
        }
        bps[r] = t;
    }
    __syncthreads();
    if (tid < 64) bpg[tid] = bps[tid];
}

// ---- k_pre_b: one coarse interval per block (65 blocks x 64 threads) ----
__global__ __launch_bounds__(64) void k_pre_b(
    const float* __restrict__ W1, const float* __restrict__ b1,
    const float* __restrict__ W2, const float* __restrict__ b2,
    const float* __restrict__ W3, const float* __restrict__ bpg,
    float* __restrict__ knots, float2* __restrict__ coef, int* __restrict__ nvalid)
{
    __shared__ float bps[64];
    const int lane = threadIdx.x;
    const int k = blockIdx.x;
    bps[lane] = bpg[lane];
    __syncthreads();

    // affine coeffs of z_i (i = lane) on interval k: z = a*x + b
    float lof = (k == 0) ? (bps[0] - 1.0f) : bps[k - 1];
    float hif = (k == 64) ? (bps[63] + 1.0f) : bps[k];
    float xm = lof + 0.5f * (hif - lof);
    float a = 0.0f, b = b2[lane];
    for (int j = 0; j < 64; ++j) {
        float w1 = W1[j];
        if (w1 * xm + b1[j] > 0.0f) {
            float w2 = W2[lane * 64 + j];
            a += w2 * w1;
            b += w2 * b1[j];
        }
    }

    // outer-relu crossing of z_i inside the open interval
    float w3 = W3[lane];
    float lo = (k == 0) ? -INFINITY : bps[k - 1];
    float hi = (k == 64) ? INFINITY : bps[k];
    float c = INFINITY, da = 0.0f, db = 0.0f;
    if (a != 0.0f) {
        float cc = -b / a;
        if (cc > lo && cc < hi) {
            float s = (a > 0.0f) ? 1.0f : -1.0f;
            c = cc; da = s * w3 * a; db = s * w3 * b;
        }
    }
    // active set just right of left edge -> (a0,b0)
    bool act;
    if (k == 0) act = (a < 0.0f) || (a == 0.0f && b > 0.0f);
    else { float v = a * lo + b; act = (v > 0.0f) || (v == 0.0f && a > 0.0f); }
    float a0 = act ? w3 * a : 0.0f;
    float b0 = act ? w3 * b : 0.0f;
    for (int d = 32; d; d >>= 1) { a0 += __shfl_xor(a0, d); b0 += __shfl_xor(b0, d); }

    // stable rank sort of crossings (inf = invalid go last)
    int rank = 0;
    for (int l = 0; l < 64; ++l) {
        float o = __shfl(c, l);
        rank += (o < c) || (o == c && l < lane);
    }
    int src = 0;
    for (int l = 0; l < 64; ++l) {
        int r = __shfl(rank, l);
        if (r == lane) src = l;
    }
    float cs  = __shfl(c, src);
    float das = __shfl(da, src);
    float dbs = __shfl(db, src);
    for (int d = 1; d < 64; d <<= 1) {  // inclusive scan in sorted order
        float ta = __shfl_up(das, d);
        float tb = __shfl_up(dbs, d);
        if (lane >= d) { das += ta; dbs += tb; }
    }
    knots[k * ROW + lane] = cs;
    if (lane == 0) coef[k * ROW] = make_float2(a0, b0);
    coef[k * ROW + lane + 1] = make_float2(a0 + das, b0 + dbs);

    unsigned long long vm = __ballot(isfinite(c));
    if (lane == 0) nvalid[k] = (int)__popcll(vm);
}

// ---- k_pre_c: flatten (k,j) tables into one sorted knot array + grid (1 block) ----
// Flat order per k: nvalid[k] fine knots, then coarse bps[k] (k<64). Globally sorted
// because fine knots lie strictly inside (bps[k-1], bps[k]).  m = #{T <= x} selects
// the SAME coefficient as the two-level search.
__global__ __launch_bounds__(256) void k_pre_c(
    const float* __restrict__ bpg, float* __restrict__ knots,
    float2* __restrict__ coef, const int* __restrict__ nvalid,
    unsigned short* __restrict__ baseg)
{
    __shared__ float  T_s[TCAP];
    __shared__ float2 C_s[MMAX];
    __shared__ int off[66];
    const int tid = threadIdx.x;
    if (tid == 0) {
        int o = 0;
        for (int k = 0; k < 65; ++k) { off[k] = o; o += nvalid[k] + 1; }
        off[65] = o;  // = M + 1 coef entries; M = o - 1 knots
    }
    __syncthreads();
    const int M = off[65] - 1;

    // phase 1: gather old layout -> flat LDS
    for (int p = tid; p < 65 * ROW; p += 256) {
        int k = p / ROW, j = p - k * ROW;
        int nv = nvalid[k];
        int o = off[k];
        if (j < nv) T_s[o + j] = knots[k * ROW + j];
        else if (j == nv && k < 64) T_s[o + j] = bpg[k];
        if (j <= nv) C_s[o + j] = coef[k * ROW + j];
    }
    float2 lastC = coef[64 * ROW + nvalid[64]];
    __syncthreads();
    for (int i = M + tid; i < TCAP; i += 256) T_s[i] = INFINITY;     // knot sentinels
    for (int i = M + 1 + tid; i < MMAX; i += 256) C_s[i] = lastC;    // coef pad
    __syncthreads();

    // phase 2: write flat tables back (in-place over knots/coef buffers) + grid
    for (int i = tid; i < TCAP; i += 256) knots[i] = T_s[i];
    for (int i = tid; i < MMAX; i += 256) coef[i] = C_s[i];
    for (int c = tid; c < NC; c += 256) {
        float left = GLO + c * DXF;
        int lo = 0, hi = M;  // lower bound: #{T <= left}
        while (lo < hi) { int mid = (lo + hi) >> 1; if (T_s[mid] <= left) lo = mid + 1; else hi = mid; }
        baseg[c] = (unsigned short)lo;
    }
}

// ---- eval: grid + branchless 12-window count + LDS-aggregated segment sums ----
__global__ __launch_bounds__(256) void k_eval(
    const float* __restrict__ x, const int* __restrict__ batch,
    const float* __restrict__ Tf, const float2* __restrict__ Cf,
    const unsigned short* __restrict__ baseg,
    unsigned long long* __restrict__ pooled, int* __restrict__ counts, int n)
{
    __shared__ __align__(16) float T_s[TCAP];        // 16960 B
    __shared__ unsigned short base_s[NC];            //  8192 B
    __shared__ unsigned long long aggP[CAP];         //   512 B
    __shared__ int aggC[CAP];                        //   256 B
    __shared__ int segFirst_s;
    const int tid = threadIdx.x;

    // stage tables (all threads participate regardless of tail)
    for (int i = tid; i < TCAP / 4; i += 256)
        ((float4*)T_s)[i] = ((const float4*)Tf)[i];
    for (int i = tid; i < NC / 2; i += 256)
        ((unsigned int*)base_s)[i] = ((const unsigned int*)baseg)[i];
    if (tid < CAP) { aggP[tid] = 0ull; aggC[tid] = 0; }

    long long base = ((long long)blockIdx.x * 256 + tid) * PPT;
    const bool active = base < n;   // n % PPT == 0 -> active threads do full vectors

    float xs[PPT]; int ss[PPT];
    if (active) {
        const float4* xp = (const float4*)(x + base);
        const int4*   bp = (const int4*)(batch + base);
#pragma unroll
        for (int v = 0; v < PPT / 4; ++v) {
            float4 xv4 = xp[v]; int4 s4 = bp[v];
            xs[4 * v + 0] = xv4.x; xs[4 * v + 1] = xv4.y; xs[4 * v + 2] = xv4.z; xs[4 * v + 3] = xv4.w;
            ss[4 * v + 0] = s4.x;  ss[4 * v + 1] = s4.y;  ss[4 * v + 2] = s4.z;  ss[4 * v + 3] = s4.w;
        }
        if (tid == 0) segFirst_s = ss[0];   // block's first (lowest) segment
    }
    __syncthreads();
    const int segFirst = segFirst_s;

    if (active) {
        int curSeg = -1; long long acc = 0; int cnt = 0;
#pragma unroll
        for (int p = 0; p < PPT; ++p) {
            float xv = xs[p];
            int m;
            if (xv >= GLO) {
                int c = (int)((xv - GLO) * INVDX);
                c = c < NC - 1 ? c : NC - 1;
                if (c > 0 && GLO + c * DXF > xv) --c;  // fp rounding guard
                int b0i = base_s[c];
                int a0 = b0i & ~3;
                // 12-entry window from a0: entries below b0i are <= x by grid
                // construction, so m = a0 + count(T[a0..a0+11] <= x).
                const float4* tw = (const float4*)(T_s + a0);
                float4 t0 = tw[0], t1 = tw[1], t2 = tw[2];
                int cw = (t0.x <= xv) + (t0.y <= xv) + (t0.z <= xv) + (t0.w <= xv)
                       + (t1.x <= xv) + (t1.y <= xv) + (t1.z <= xv) + (t1.w <= xv)
                       + (t2.x <= xv) + (t2.y <= xv) + (t2.z <= xv) + (t2.w <= xv);
                m = a0 + cw;
                if (cw == 12) { while (T_s[m] <= xv) ++m; }  // ~never taken
            } else m = 0;
            float2 ab = Cf[m];                 // 34 KB table, L1/L2 resident
            float g = fmaf(ab.x, xv, ab.y);
            long long q = (long long)(g * SCALEF);  // exact: *2^30 is exponent shift
            int s = ss[p];
            if (s != curSeg) {
                if (cnt) {
                    int idx = curSeg - segFirst;
                    if (idx < CAP) {
                        atomicAdd(&aggP[idx], (unsigned long long)acc);
                        atomicAdd(&aggC[idx], cnt);
                    } else {
                        atomicAdd(&pooled[curSeg], (unsigned long long)acc);
                        atomicAdd(&counts[curSeg], cnt);
                    }
                }
                curSeg = s; acc = q; cnt = 1;
            } else { acc += q; ++cnt; }
        }
        if (cnt) {
            int idx = curSeg - segFirst;
            if (idx < CAP) {
                atomicAdd(&aggP[idx], (unsigned long long)acc);
                atomicAdd(&aggC[idx], cnt);
            } else {
                atomicAdd(&pooled[curSeg], (unsigned long long)acc);
                atomicAdd(&counts[curSeg], cnt);
            }
        }
    }
    __syncthreads();
    if (tid < CAP) {
        int c = aggC[tid];
        if (c) {
            atomicAdd(&pooled[segFirst + tid], aggP[tid]);
            atomicAdd(&counts[segFirst + tid], c);
        }
    }
}

// ---- per-segment weight ----
__global__ void k_weights(const unsigned long long* __restrict__ pooled,
                          const int* __restrict__ counts,
                          const float* __restrict__ b3,
                          float* __restrict__ weights)
{
    int s = blockIdx.x * blockDim.x + threadIdx.x;
    if (s >= NSEG) return;
    long long p = (long long)pooled[s];
    int c = counts[s];
    double mean = ((double)p / SCALE) / (double)(c > 0 ? c : 1);
    float w = (float)(mean + (double)b3[0]);
    weights[s] = fmaxf(w, 0.0f);
}

// ---- broadcast back to points ----
__global__ __launch_bounds__(256) void k_scatter(
    const int* __restrict__ batch, const float* __restrict__ weights,
    float* __restrict__ out, int n)
{
    long long base = ((long long)blockIdx.x * 256 + threadIdx.x) * SPPT;
    if (base >= n) return;
    const int4* bt = (const int4*)(batch + base);
    int4 b0 = bt[0], b1 = bt[1];
    float4 o0, o1;
    o0.x = weights[b0.x];  // sorted batch -> ~1 distinct line per wave, L1 hit
    o0.y = weights[b0.y];
    o0.z = weights[b0.z];
    o0.w = weights[b0.w];
    o1.x = weights[b1.x];
    o1.y = weights[b1.y];
    o1.z = weights[b1.z];
    o1.w = weights[b1.w];
    float4* op = (float4*)(out + base);
    op[0] = o0;
    op[1] = o1;
}

extern "C" void kernel_launch(void* const* d_in, const int* in_sizes, int n_in,
                              void* d_out, int out_size, void* d_ws, size_t ws_size,
                              hipStream_t stream)
{
    const float* x   = (const float*)d_in[0];
    const int* batch = (const int*)d_in[1];
    const float* W1 = (const float*)d_in[2];
    const float* b1 = (const float*)d_in[3];
    const float* W2 = (const float*)d_in[4];
    const float* b2 = (const float*)d_in[5];
    const float* W3 = (const float*)d_in[6];
    const float* b3 = (const float*)d_in[7];
    float* out = (float*)d_out;
    const int n = in_sizes[0];

    char* ws = (char*)d_ws;
    unsigned long long* pooled = (unsigned long long*)ws;   // 16384
    int*    counts  = (int*)(ws + 16384);                   // 8192
    float*  weights = (float*)(ws + 24576);                 // 8192
    float*  bpg     = (float*)(ws + 32768);                 // 256
    int*    nvalid  = (int*)(ws + 33024);                   // 272
    float*  knots   = (float*)(ws + 33296);                 // 65*65 then flat T[TCAP]: 16960
    float2* coef    = (float2*)(ws + 50256);                // 65*65 then flat C[MMAX]: 33808
    unsigned short* baseg = (unsigned short*)(ws + 84064);  // 8192 -> total ~92.3 KB

    k_pre_a<<<1, 256, 0, stream>>>(W1, b1, pooled, counts, bpg);
    k_pre_b<<<65, 64, 0, stream>>>(W1, b1, W2, b2, W3, bpg, knots, coef, nvalid);
    k_pre_c<<<1, 256, 0, stream>>>(bpg, knots, coef, nvalid, baseg);

    const int eblocks = (int)((n + 256LL * PPT - 1) / (256LL * PPT));
    k_eval<<<eblocks, 256, 0, stream>>>(x, batch, knots, coef, baseg, pooled, counts, n);
    k_weights<<<(NSEG + 255) / 256, 256, 0, stream>>>(pooled, counts, b3, weights);
    const int sblocks = (int)((n + 256LL * SPPT - 1) / (256LL * SPPT));
    k_scatter<<<sblocks, 256, 0, stream>>>(batch, weights, out, n);
}